// Round 1
// baseline (683.645 us; speedup 1.0000x reference)
//
#include <hip/hip_runtime.h>
#include <math.h>

// Problem constants
#define B_    8
#define N_    4096
#define DF_   768
#define K1_   8
#define K2_   2
#define DS_   128
#define KVQ_  128
#define BK_   64          // B*K1
#define R_    32768       // B*N
#define SCALE_ 0.08838834764831843f

// ---- workspace layout (float offsets) ----
// total ≈ 9.3M floats ≈ 37.2 MB
static const size_t OFF_MEAN  = 0;         // 32768
static const size_t OFF_VAR   = 32768;     // 32768
static const size_t OFF_DENOM = 65536;     // 64
static const size_t OFF_GSUM  = 65600;     // 256 (j<128: K, j>=128: V)
static const size_t OFF_BIAS  = 65856;     // 256 (Kbias | Vbias)
static const size_t OFF_QKB   = 66112;     // 128
static const size_t OFF_S     = 66240;     // 128
static const size_t OFF_SLOTS = 66560;     // 16384  [bk*2+i][128]
static const size_t OFF_Q     = 82944;     // 16384
static const size_t OFF_U     = 99328;     // 16384
static const size_t OFF_ALPHA = 115712;    // 262144 [bk][n]
static const size_t OFF_ATTN  = 377856;    // 524288 [bk][i][n]
static const size_t OFF_KT    = 902144;    // 4194304 KbaseT [b][j][n]
static const size_t OFF_VN    = 5096448;   // 4194304 Vbase  [b][n][j]

__device__ __forceinline__ float wred64(float v) {
#pragma unroll
  for (int off = 32; off > 0; off >>= 1) v += __shfl_xor(v, off, 64);
  return v;
}

// block reduce for 128-thread blocks; returns (sum a, sum b) to all threads
__device__ __forceinline__ float2 bred128(float a, float b, float* red4, int t) {
  float ra = wred64(a), rb = wred64(b);
  int wid = t >> 6;
  if ((t & 63) == 0) { red4[wid] = ra; red4[2 + wid] = rb; }
  __syncthreads();
  float2 o; o.x = red4[0] + red4[1]; o.y = red4[2] + red4[3];
  __syncthreads();
  return o;
}

// ---- 1. fold ln gain/bias into projection weights: gsum[j], bias[j] ----
__global__ __launch_bounds__(64) void prep_k(
    const float* __restrict__ Wk, const float* __restrict__ Wv,
    const float* __restrict__ g, const float* __restrict__ bb,
    float* __restrict__ gsum, float* __restrict__ biasArr)
{
  int j = blockIdx.x, lane = threadIdx.x;
  const float* w = (j < 128) ? (Wk + (size_t)j*768) : (Wv + (size_t)(j-128)*768);
  float gs = 0.f, bs = 0.f;
#pragma unroll
  for (int s = 0; s < 12; ++s) {
    int dd = lane + s*64;
    float wv = w[dd];
    gs += g[dd]*wv; bs += bb[dd]*wv;
  }
  gs = wred64(gs); bs = wred64(bs);
  if (lane == 0) { gsum[j] = gs; biasArr[j] = bs; }
}

// ---- 2. per-row mean/var of tokens (one wave per row) ----
__global__ __launch_bounds__(256) void row_stats_k(
    const float* __restrict__ A, float* __restrict__ meanArr, float* __restrict__ varArr)
{
  int w = threadIdx.x >> 6, lane = threadIdx.x & 63;
  int row = blockIdx.x*4 + w;
  const float4* ap = (const float4*)(A + (size_t)row*768);
  float s = 0.f, s2 = 0.f;
#pragma unroll
  for (int k = 0; k < 3; ++k) {
    float4 v4 = ap[lane + k*64];
    s  += v4.x + v4.y + v4.z + v4.w;
    s2 += v4.x*v4.x + v4.y*v4.y + v4.z*v4.z + v4.w*v4.w;
  }
  s = wred64(s); s2 = wred64(s2);
  if (lane == 0) {
    float m = s*(1.f/768.f);
    meanArr[row] = m;
    varArr[row] = s2*(1.f/768.f) - m*m;
  }
}

// ---- 3. denom[bk] = mean(parent_masks over N) ----
__global__ __launch_bounds__(256) void denom_k(
    const float* __restrict__ pm, float* __restrict__ denomArr)
{
  __shared__ float red4[4];
  int bk = blockIdx.x, t = threadIdx.x;
  float s = 0.f;
#pragma unroll
  for (int k = 0; k < 16; ++k) s += pm[bk*4096 + t + k*256];
  s = wred64(s);
  if ((t & 63) == 0) red4[t >> 6] = s;
  __syncthreads();
  if (t == 0) denomArr[bk] = (red4[0]+red4[1]+red4[2]+red4[3])*(1.f/4096.f);
}

// ---- 4. alpha[bk][n] = c / sqrt(c^2*var + 1e-5) ----
__global__ __launch_bounds__(256) void alpha_k(
    const float* __restrict__ pm, const float* __restrict__ denomArr,
    const float* __restrict__ varArr, float* __restrict__ alpha)
{
  int idx = blockIdx.x*256 + threadIdx.x;
  int bk = idx >> 12, n = idx & 4095, b = bk >> 3;
  float den = denomArr[bk];
  float c = (den > 1e-6f) ? (pm[idx]/(den + 1e-6f)) : 1.f;
  float v = varArr[b*4096 + n];
  alpha[idx] = c*rsqrtf(c*c*v + 1e-5f);
}

// ---- 5. GEMM: [32768,768] x [768,256] -> KbaseT [b][j][n] / Vbase [b][n][j] ----
// fp32 tiled, 128x128 tile, 8x8 micro-tile, BK=16
__global__ __launch_bounds__(256, 2) void gemm_kv(
    const float* __restrict__ A, const float* __restrict__ Wk,
    const float* __restrict__ Wv, const float* __restrict__ g,
    const float* __restrict__ meanArr, const float* __restrict__ gsum,
    float* __restrict__ kt, float* __restrict__ vn)
{
  __shared__ float As[16][128];
  __shared__ float Ws[16][128];
  int jb = blockIdx.x & 1;
  int rb = blockIdx.x >> 1;
  int r0 = rb*128, j0 = jb*128;
  int t = threadIdx.x;
  int tx = t & 15, ty = t >> 4;
  float acc[8][8];
#pragma unroll
  for (int a = 0; a < 8; ++a)
#pragma unroll
    for (int c = 0; c < 8; ++c) acc[a][c] = 0.f;

  int lrow = t >> 1;
  int lseg = (t & 1)*8;
  int jj = j0 + lrow;
  const float* wsrc = (jj < 128) ? (Wk + (size_t)jj*768) : (Wv + (size_t)(jj-128)*768);
  const float* asrc = A + (size_t)(r0 + lrow)*768;

  for (int k0 = 0; k0 < 768; k0 += 16) {
    float4 a0 = *(const float4*)(asrc + k0 + lseg);
    float4 a1 = *(const float4*)(asrc + k0 + lseg + 4);
    float4 w0 = *(const float4*)(wsrc + k0 + lseg);
    float4 w1 = *(const float4*)(wsrc + k0 + lseg + 4);
    float4 g0 = *(const float4*)(g + k0 + lseg);
    float4 g1 = *(const float4*)(g + k0 + lseg + 4);
    As[lseg+0][lrow] = a0.x; As[lseg+1][lrow] = a0.y;
    As[lseg+2][lrow] = a0.z; As[lseg+3][lrow] = a0.w;
    As[lseg+4][lrow] = a1.x; As[lseg+5][lrow] = a1.y;
    As[lseg+6][lrow] = a1.z; As[lseg+7][lrow] = a1.w;
    Ws[lseg+0][lrow] = w0.x*g0.x; Ws[lseg+1][lrow] = w0.y*g0.y;
    Ws[lseg+2][lrow] = w0.z*g0.z; Ws[lseg+3][lrow] = w0.w*g0.w;
    Ws[lseg+4][lrow] = w1.x*g1.x; Ws[lseg+5][lrow] = w1.y*g1.y;
    Ws[lseg+6][lrow] = w1.z*g1.z; Ws[lseg+7][lrow] = w1.w*g1.w;
    __syncthreads();
#pragma unroll
    for (int kk = 0; kk < 16; ++kk) {
      float av[8], wv[8];
      *(float4*)(av)   = *(const float4*)(&As[kk][ty*8]);
      *(float4*)(av+4) = *(const float4*)(&As[kk][ty*8+4]);
      *(float4*)(wv)   = *(const float4*)(&Ws[kk][tx*8]);
      *(float4*)(wv+4) = *(const float4*)(&Ws[kk][tx*8+4]);
#pragma unroll
      for (int mi = 0; mi < 8; ++mi)
#pragma unroll
        for (int ji = 0; ji < 8; ++ji)
          acc[mi][ji] += av[mi]*wv[ji];
    }
    __syncthreads();
  }
#pragma unroll
  for (int mi = 0; mi < 8; ++mi) {
    int r = r0 + ty*8 + mi;
    float mr = meanArr[r];
    int b = r >> 12, n = r & 4095;
    if (jb == 0) {
#pragma unroll
      for (int ji = 0; ji < 8; ++ji) {
        int j = tx*8 + ji;
        kt[((size_t)(b*128 + j))*4096 + n] = acc[mi][ji] - mr*gsum[j];
      }
    } else {
      float* vrow = vn + ((size_t)(b*4096 + n))*128 + tx*8;
#pragma unroll
      for (int ji = 0; ji < 8; ++ji) {
        int j = 128 + tx*8 + ji;
        vrow[ji] = acc[mi][ji] - mr*gsum[j];
      }
    }
  }
}

// ---- 6. slots init ----
__global__ __launch_bounds__(256) void slots_init_k(
    const float* __restrict__ ps, const float* __restrict__ eps,
    float* __restrict__ slots)
{
  int bk = blockIdx.x, t = threadIdx.x;
  int d = t & 127;
  slots[bk*256 + t] = ps[bk*128 + d] + 0.01f*eps[bk*256 + t];
}

// ---- 7. per-iter: LN(slots) -> q, qKbias; zero U/S ----
__global__ __launch_bounds__(128) void slots_q_k(
    const float* __restrict__ slots, const float* __restrict__ g_s,
    const float* __restrict__ b_s, const float* __restrict__ Wq,
    const float* __restrict__ biasArr,
    float* __restrict__ q, float* __restrict__ qkb,
    float* __restrict__ U, float* __restrict__ Ssum)
{
  __shared__ float sn[128];
  __shared__ float red4[4];
  int row = blockIdx.x, d = threadIdx.x;
  float x = slots[row*128 + d];
  float2 mv = bred128(x, x*x, red4, d);
  float m = mv.x*(1.f/128.f);
  float v = mv.y*(1.f/128.f) - m*m;
  float snd = (x - m)*rsqrtf(v + 1e-5f)*g_s[d] + b_s[d];
  sn[d] = snd;
  __syncthreads();
  float acc = 0.f;
  const float* wqr = Wq + (size_t)d*128;
#pragma unroll 4
  for (int e = 0; e < 128; ++e) acc += sn[e]*wqr[e];
  q[row*128 + d] = acc;
  float2 qb = bred128(acc*biasArr[d], 0.f, red4, d);
  if (d == 0) { qkb[row] = qb.x; Ssum[row] = 0.f; }
  U[row*128 + d] = 0.f;
}

__device__ __forceinline__ void soft2(float a0, float a1, float al,
                                      float qb0, float qb1,
                                      float& o0, float& o1) {
  float d0 = SCALE_*(al*a0 + qb0);
  float d1 = SCALE_*(al*a1 + qb1);
  float mx = fmaxf(d0, d1);
  float e0 = expf(d0 - mx), e1 = expf(d1 - mx);
  float inv = 1.f/(e0 + e1);
  o0 = e0*inv + 1e-8f;
  o1 = e1*inv + 1e-8f;
}

// ---- 8. per-iter: dots + softmax over K2=2 + S partial sums ----
__global__ __launch_bounds__(256) void attn_dots_k(
    const float* __restrict__ kt, const float* __restrict__ q,
    const float* __restrict__ qkb, const float* __restrict__ alpha,
    float* __restrict__ attn, float* __restrict__ Ssum)
{
  __shared__ float qs[256];
  __shared__ float red8[8];
  int bk = blockIdx.x >> 2, ch = blockIdx.x & 3;
  int t = threadIdx.x;
  int b = bk >> 3;
  qs[t] = q[bk*256 + t];
  __syncthreads();
  int n = ch*1024 + t*4;
  const float* ktb = kt + (size_t)b*128*4096 + n;
  float a0x=0,a0y=0,a0z=0,a0w=0, a1x=0,a1y=0,a1z=0,a1w=0;
#pragma unroll 8
  for (int j = 0; j < 128; ++j) {
    float4 kv = *(const float4*)(ktb + (size_t)j*4096);
    float q0 = qs[j], q1 = qs[128+j];
    a0x += kv.x*q0; a0y += kv.y*q0; a0z += kv.z*q0; a0w += kv.w*q0;
    a1x += kv.x*q1; a1y += kv.y*q1; a1z += kv.z*q1; a1w += kv.w*q1;
  }
  float qb0 = qkb[bk*2+0], qb1 = qkb[bk*2+1];
  float4 al = *(const float4*)(alpha + bk*4096 + n);
  float4 o0, o1;
  soft2(a0x,a1x,al.x,qb0,qb1,o0.x,o1.x);
  soft2(a0y,a1y,al.y,qb0,qb1,o0.y,o1.y);
  soft2(a0z,a1z,al.z,qb0,qb1,o0.z,o1.z);
  soft2(a0w,a1w,al.w,qb0,qb1,o0.w,o1.w);
  *(float4*)(attn + bk*8192 + n) = o0;
  *(float4*)(attn + bk*8192 + 4096 + n) = o1;
  float s0 = o0.x+o0.y+o0.z+o0.w;
  float s1 = o1.x+o1.y+o1.z+o1.w;
  s0 = wred64(s0); s1 = wred64(s1);
  int wid = t >> 6;
  if ((t & 63) == 0) { red8[wid] = s0; red8[4+wid] = s1; }
  __syncthreads();
  if (t == 0) {
    atomicAdd(&Ssum[bk*2+0], red8[0]+red8[1]+red8[2]+red8[3]);
    atomicAdd(&Ssum[bk*2+1], red8[4]+red8[5]+red8[6]+red8[7]);
  }
}

// ---- 9. per-iter: U[bk][i][:] += sum_n attn*alpha*Vbase ----
__global__ __launch_bounds__(256) void attn_updates_k(
    const float* __restrict__ vn, const float* __restrict__ attn,
    const float* __restrict__ alpha, float* __restrict__ U)
{
  int bk = blockIdx.x >> 3, ch = blockIdx.x & 7;
  int t = threadIdx.x;
  int i = t >> 7, d = t & 127;
  int b = bk >> 3;
  const float* vb = vn + (size_t)b*4096*128 + d;
  const float* at = attn + bk*8192 + i*4096;
  const float* al = alpha + bk*4096;
  float acc = 0.f;
  int n0 = ch*512;
#pragma unroll 4
  for (int n = n0; n < n0+512; ++n) {
    float w = at[n]*al[n];
    acc += w * vb[(size_t)n*128];
  }
  atomicAdd(&U[bk*256 + t], acc);
}

// ---- 10. per-iter: finalize updates, GRU cell, LN, MLP ----
__global__ __launch_bounds__(128) void gru_mlp_k(
    const float* __restrict__ U, const float* __restrict__ Ssum,
    const float* __restrict__ biasArr,
    const float* __restrict__ Wih, const float* __restrict__ Whh,
    const float* __restrict__ bih, const float* __restrict__ bhh,
    const float* __restrict__ mlp_g, const float* __restrict__ mlp_b,
    const float* __restrict__ W1, const float* __restrict__ b1,
    const float* __restrict__ W2, const float* __restrict__ b2,
    float* __restrict__ slots, float* __restrict__ outObj, int last)
{
  __shared__ float xs[128], hs[128], hn[128], t1s[512];
  __shared__ float red4[4];
  int row = blockIdx.x;
  int d = threadIdx.x;
  float S = Ssum[row];
  float u = U[row*128 + d]/S + biasArr[128 + d];
  float h0 = slots[row*128 + d];
  xs[d] = u; hs[d] = h0;
  __syncthreads();
  float gir = bih[d], giz = bih[128+d], gin = bih[256+d];
  float ghr = bhh[d], ghz = bhh[128+d], ghn = bhh[256+d];
  const float* wih_r = Wih + (size_t)d*128;
  const float* wih_z = Wih + (size_t)(128+d)*128;
  const float* wih_n = Wih + (size_t)(256+d)*128;
  const float* whh_r = Whh + (size_t)d*128;
  const float* whh_z = Whh + (size_t)(128+d)*128;
  const float* whh_n = Whh + (size_t)(256+d)*128;
#pragma unroll 4
  for (int e = 0; e < 128; ++e) {
    float x = xs[e], hh = hs[e];
    gir += x*wih_r[e]; giz += x*wih_z[e]; gin += x*wih_n[e];
    ghr += hh*whh_r[e]; ghz += hh*whh_z[e]; ghn += hh*whh_n[e];
  }
  float r = 1.f/(1.f + expf(-(gir+ghr)));
  float z = 1.f/(1.f + expf(-(giz+ghz)));
  float nn = tanhf(gin + r*ghn);
  float hp = (1.f - z)*nn + z*h0;
  float2 mv = bred128(hp, hp*hp, red4, d);
  float m = mv.x*(1.f/128.f);
  float v = mv.y*(1.f/128.f) - m*m;
  float hnd = (hp - m)*rsqrtf(v + 1e-5f)*mlp_g[d] + mlp_b[d];
  hn[d] = hnd;
  __syncthreads();
#pragma unroll
  for (int qd = 0; qd < 4; ++qd) {
    int e = qd*128 + d;
    float a = b1[e];
    const float* w1r = W1 + (size_t)e*128;
#pragma unroll 4
    for (int f = 0; f < 128; ++f) a += hn[f]*w1r[f];
    t1s[e] = 0.5f*a*(1.f + erff(a*0.70710678118654752f));
  }
  __syncthreads();
  float o = b2[d];
  const float* w2r = W2 + (size_t)d*512;
#pragma unroll 4
  for (int e = 0; e < 512; ++e) o += t1s[e]*w2r[e];
  slots[row*128 + d] = o;
  if (last) outObj[row*128 + d] = o;
}

// ---- 11. gating: out = attn_last * parent_masks ----
__global__ __launch_bounds__(256) void gating_k(
    const float* __restrict__ attn, const float* __restrict__ pm,
    float* __restrict__ outG)
{
  int idx = blockIdx.x*256 + threadIdx.x;
  int bk = idx >> 13;
  int n = idx & 4095;
  outG[idx] = attn[idx] * pm[bk*4096 + n];
}

extern "C" void kernel_launch(void* const* d_in, const int* in_sizes, int n_in,
                              void* d_out, int out_size, void* d_ws, size_t ws_size,
                              hipStream_t stream) {
  const float* tokens = (const float*)d_in[0];
  const float* pslots = (const float*)d_in[1];
  const float* pmasks = (const float*)d_in[2];
  const float* eps    = (const float*)d_in[3];
  const float* ln_in_g= (const float*)d_in[4];
  const float* ln_in_b= (const float*)d_in[5];
  const float* ln_s_g = (const float*)d_in[6];
  const float* ln_s_b = (const float*)d_in[7];
  const float* Wq     = (const float*)d_in[8];
  const float* Wk     = (const float*)d_in[9];
  const float* Wv     = (const float*)d_in[10];
  const float* Wih    = (const float*)d_in[11];
  const float* Whh    = (const float*)d_in[12];
  const float* bih    = (const float*)d_in[13];
  const float* bhh    = (const float*)d_in[14];
  const float* mlp_g  = (const float*)d_in[15];
  const float* mlp_b  = (const float*)d_in[16];
  const float* W1     = (const float*)d_in[17];
  const float* b1     = (const float*)d_in[18];
  const float* W2     = (const float*)d_in[19];
  const float* b2     = (const float*)d_in[20];
  float* ws  = (float*)d_ws;
  float* out = (float*)d_out;

  prep_k<<<256, 64, 0, stream>>>(Wk, Wv, ln_in_g, ln_in_b,
                                 ws+OFF_GSUM, ws+OFF_BIAS);
  row_stats_k<<<R_/4, 256, 0, stream>>>(tokens, ws+OFF_MEAN, ws+OFF_VAR);
  denom_k<<<BK_, 256, 0, stream>>>(pmasks, ws+OFF_DENOM);
  alpha_k<<<BK_*N_/256, 256, 0, stream>>>(pmasks, ws+OFF_DENOM, ws+OFF_VAR,
                                          ws+OFF_ALPHA);
  gemm_kv<<<512, 256, 0, stream>>>(tokens, Wk, Wv, ln_in_g,
                                   ws+OFF_MEAN, ws+OFF_GSUM,
                                   ws+OFF_KT, ws+OFF_VN);
  slots_init_k<<<BK_, 256, 0, stream>>>(pslots, eps, ws+OFF_SLOTS);

  for (int it = 0; it < 3; ++it) {
    slots_q_k<<<128, 128, 0, stream>>>(ws+OFF_SLOTS, ln_s_g, ln_s_b, Wq,
                                       ws+OFF_BIAS, ws+OFF_Q, ws+OFF_QKB,
                                       ws+OFF_U, ws+OFF_S);
    attn_dots_k<<<BK_*4, 256, 0, stream>>>(ws+OFF_KT, ws+OFF_Q, ws+OFF_QKB,
                                           ws+OFF_ALPHA, ws+OFF_ATTN, ws+OFF_S);
    attn_updates_k<<<BK_*8, 256, 0, stream>>>(ws+OFF_VN, ws+OFF_ATTN,
                                              ws+OFF_ALPHA, ws+OFF_U);
    gru_mlp_k<<<128, 128, 0, stream>>>(ws+OFF_U, ws+OFF_S, ws+OFF_BIAS,
                                       Wih, Whh, bih, bhh, mlp_g, mlp_b,
                                       W1, b1, W2, b2,
                                       ws+OFF_SLOTS, out, (it == 2) ? 1 : 0);
  }
  gating_k<<<BK_*K2_*N_/256, 256, 0, stream>>>(ws+OFF_ATTN, pmasks, out + 16384);
}

// Round 2
// 541.498 us; speedup vs baseline: 1.2625x; 1.2625x over previous
//
#include <hip/hip_runtime.h>
#include <math.h>

#define SCALE_ 0.08838834764831843f

typedef __attribute__((ext_vector_type(8))) short bf16x8;
typedef __attribute__((ext_vector_type(4))) float f32x4;

// ---- workspace layout (float offsets), total 9323328 floats = 37.3 MB ----
static const size_t OFF_VAR   = 0;        // 32768  var(tokens) per (b,n)
static const size_t OFF_DENOM = 32768;    // 64
static const size_t OFF_GSUM  = 32832;    // 256  sum_k g*W  (K|V)
static const size_t OFF_BIAS  = 33088;    // 256  sum_k b*W  (Kbias|Vbias)
static const size_t OFF_QKB   = 33344;    // 128  q·Kbias per slot row
static const size_t OFF_SSUM  = 33472;    // 128
static const size_t OFF_SLOTS = 33600;    // 16384 [row=bk*2+i][128]
static const size_t OFF_Q     = 49984;    // 16384
static const size_t OFF_WQT   = 66368;    // 16384
static const size_t OFF_WIHT  = 82752;    // 49152 [e][384]
static const size_t OFF_WHHT  = 131904;   // 49152
static const size_t OFF_W1T   = 181056;   // 65536 [f][512]
static const size_t OFF_W2T   = 246592;   // 65536 [e][128]
static const size_t OFF_W2BF  = 312128;   // 98304 float-slots = 196608 bf16 [j][768]
static const size_t OFF_UPART = 410432;   // 524288 [bi(256)][16][128]
static const size_t OFF_KV    = 934720;   // 8388608 [b][n][256] (K|V)

__device__ __forceinline__ float wred64(float v) {
#pragma unroll
  for (int off = 32; off > 0; off >>= 1) v += __shfl_xor(v, off, 64);
  return v;
}

__device__ __forceinline__ float2 bred128(float a, float b, float* red4, int t) {
  float ra = wred64(a), rb = wred64(b);
  int wid = t >> 6;
  if ((t & 63) == 0) { red4[wid] = ra; red4[2 + wid] = rb; }
  __syncthreads();
  float2 o; o.x = red4[0] + red4[1]; o.y = red4[2] + red4[3];
  __syncthreads();
  return o;
}

__device__ __forceinline__ unsigned short f2bf(float f) {
  unsigned u = __float_as_uint(f);
  unsigned r = (u + 0x7fffu + ((u >> 16) & 1u)) >> 16;
  return (unsigned short)r;
}

// ---- 1. fold ln gain into W (bf16) + gsum/bias sums ----
__global__ __launch_bounds__(64) void prep_w_k(
    const float* __restrict__ Wk, const float* __restrict__ Wv,
    const float* __restrict__ g, const float* __restrict__ bb,
    unsigned short* __restrict__ w2, float* __restrict__ gsum,
    float* __restrict__ biasArr)
{
  int j = blockIdx.x, lane = threadIdx.x;
  const float* w = (j < 128) ? (Wk + (size_t)j*768) : (Wv + (size_t)(j-128)*768);
  float gs = 0.f, bs = 0.f;
#pragma unroll
  for (int s = 0; s < 12; ++s) {
    int dd = lane + s*64;
    float wv = w[dd], gv = g[dd];
    gs += gv*wv; bs += bb[dd]*wv;
    w2[(size_t)j*768 + dd] = f2bf(wv*gv);
  }
  gs = wred64(gs); bs = wred64(bs);
  if (lane == 0) { gsum[j] = gs; biasArr[j] = bs; }
}

// ---- 2. weight transposes for coalesced per-slot GEMV ----
__global__ __launch_bounds__(256) void prep_T_k(
    const float* __restrict__ Wq, const float* __restrict__ Wih,
    const float* __restrict__ Whh, const float* __restrict__ W1,
    const float* __restrict__ W2,
    float* __restrict__ WqT, float* __restrict__ WihT,
    float* __restrict__ WhhT, float* __restrict__ W1T, float* __restrict__ W2T)
{
  int bi = blockIdx.x, t = threadIdx.x;
  const float* src; float* dst; int R, C, idx;
  if (bi < 64)       { src = Wq;  dst = WqT;  R = 128; C = 128; idx = bi*256 + t; }
  else if (bi < 256) { src = Wih; dst = WihT; R = 384; C = 128; idx = (bi-64)*256 + t; }
  else if (bi < 448) { src = Whh; dst = WhhT; R = 384; C = 128; idx = (bi-256)*256 + t; }
  else if (bi < 704) { src = W1;  dst = W1T;  R = 512; C = 128; idx = (bi-448)*256 + t; }
  else               { src = W2;  dst = W2T;  R = 128; C = 512; idx = (bi-704)*256 + t; }
  int r, c;
  if (C == 128) { r = idx >> 7; c = idx & 127; } else { r = idx >> 9; c = idx & 511; }
  dst[(size_t)c*R + r] = src[idx];
}

// ---- 3. denom[bk] = mean(parent_masks over N) ----
__global__ __launch_bounds__(256) void denom_k(
    const float* __restrict__ pm, float* __restrict__ denomArr)
{
  __shared__ float red4[4];
  int bk = blockIdx.x, t = threadIdx.x;
  float s = 0.f;
#pragma unroll
  for (int k = 0; k < 16; ++k) s += pm[bk*4096 + t + k*256];
  s = wred64(s);
  if ((t & 63) == 0) red4[t >> 6] = s;
  __syncthreads();
  if (t == 0) denomArr[bk] = (red4[0]+red4[1]+red4[2]+red4[3])*(1.f/4096.f);
}

// ---- 4. MFMA GEMM: tokens[32768,768]fp32 -> bf16 x W2[256,768]bf16 ----
//      epilogue: KV[b][n][j] = acc - mean_row*gsum[j]; also writes varArr.
__global__ __launch_bounds__(256) void gemm_kv_k(
    const float* __restrict__ tokens, const unsigned short* __restrict__ w2,
    const float* __restrict__ gsum, float* __restrict__ KV,
    float* __restrict__ varArr)
{
  __shared__ unsigned short As[128*64];
  __shared__ unsigned short Bs[128*64];
  int bi = blockIdx.x;
  int jb = bi & 1, rb = bi >> 1;
  int r0 = rb*128, j0 = jb*128;
  int t = threadIdx.x;
  int w = t >> 6, lane = t & 63;
  int j4 = t & 15, rowb = t >> 4;
  int m0w = (w >> 1)*64, n0w = (w & 1)*64;
  int lm = lane & 15, lq = lane >> 4;

  f32x4 acc[4][4];
#pragma unroll
  for (int a = 0; a < 4; ++a)
#pragma unroll
    for (int c = 0; c < 4; ++c) acc[a][c] = f32x4{0.f, 0.f, 0.f, 0.f};

  float s1[8], s2[8];
#pragma unroll
  for (int s = 0; s < 8; ++s) { s1[s] = 0.f; s2[s] = 0.f; }

  for (int k0 = 0; k0 < 768; k0 += 64) {
    __syncthreads();
    // B tile: async global->LDS, bf16, 4 x 1KB per wave
#pragma unroll
    for (int s = 0; s < 4; ++s) {
      int row = w*32 + s*8;
      __builtin_amdgcn_global_load_lds(
        (const __attribute__((address_space(1))) void*)
          (w2 + (size_t)(j0 + row + (lane >> 3))*768 + k0 + (lane & 7)*8),
        (__attribute__((address_space(3))) void*)(&Bs[row*64]), 16, 0, 0);
    }
    // A tile: fp32 load + stats + bf16 cvt + LDS write
#pragma unroll
    for (int s = 0; s < 8; ++s) {
      int row = rowb + s*16;
      float4 x = *(const float4*)(tokens + (size_t)(r0 + row)*768 + k0 + j4*4);
      s1[s] += x.x + x.y + x.z + x.w;
      s2[s] += x.x*x.x + x.y*x.y + x.z*x.z + x.w*x.w;
      unsigned lo = (unsigned)f2bf(x.x) | ((unsigned)f2bf(x.y) << 16);
      unsigned hi = (unsigned)f2bf(x.z) | ((unsigned)f2bf(x.w) << 16);
      *(uint2*)(&As[row*64 + j4*4]) = make_uint2(lo, hi);
    }
    __syncthreads();
#pragma unroll
    for (int kk = 0; kk < 64; kk += 32) {
      bf16x8 af[4], bfr[4];
#pragma unroll
      for (int mt = 0; mt < 4; ++mt)
        af[mt] = *(const bf16x8*)(&As[(m0w + mt*16 + lm)*64 + kk + lq*8]);
#pragma unroll
      for (int nt = 0; nt < 4; ++nt)
        bfr[nt] = *(const bf16x8*)(&Bs[(n0w + nt*16 + lm)*64 + kk + lq*8]);
#pragma unroll
      for (int mt = 0; mt < 4; ++mt)
#pragma unroll
        for (int nt = 0; nt < 4; ++nt)
          acc[mt][nt] = __builtin_amdgcn_mfma_f32_16x16x32_bf16(
              af[mt], bfr[nt], acc[mt][nt], 0, 0, 0);
    }
  }
  __syncthreads();
  float* meanS = (float*)As;   // reuse LDS
#pragma unroll
  for (int s = 0; s < 8; ++s) {
#pragma unroll
    for (int m = 8; m >= 1; m >>= 1) {
      s1[s] += __shfl_xor(s1[s], m, 16);
      s2[s] += __shfl_xor(s2[s], m, 16);
    }
  }
  if (j4 == 0) {
#pragma unroll
    for (int s = 0; s < 8; ++s) {
      int row = rowb + s*16;
      float m = s1[s]*(1.f/768.f);
      meanS[row] = m;
      if (jb == 0) varArr[r0 + row] = s2[s]*(1.f/768.f) - m*m;
    }
  }
  __syncthreads();
#pragma unroll
  for (int nt = 0; nt < 4; ++nt) {
    int jg = j0 + n0w + nt*16 + lm;
    float gs = gsum[jg];
#pragma unroll
    for (int mt = 0; mt < 4; ++mt) {
#pragma unroll
      for (int reg = 0; reg < 4; ++reg) {
        int rl = m0w + mt*16 + lq*4 + reg;
        KV[(size_t)(r0 + rl)*256 + jg] = acc[mt][nt][reg] - meanS[rl]*gs;
      }
    }
  }
}

// ---- 5. slots init + LN + q (iter 0) ----
__global__ __launch_bounds__(128) void slots_init_q_k(
    const float* __restrict__ ps, const float* __restrict__ eps,
    const float* __restrict__ g_s, const float* __restrict__ b_s,
    const float* __restrict__ WqT, const float* __restrict__ biasArr,
    float* __restrict__ slots, float* __restrict__ qg, float* __restrict__ qkb,
    float* __restrict__ Ssum)
{
  __shared__ float sn[128];
  __shared__ float red4[4];
  int row = blockIdx.x, d = threadIdx.x, bk = row >> 1;
  float x = ps[bk*128 + d] + 0.01f*eps[row*128 + d];
  slots[row*128 + d] = x;
  float2 mv = bred128(x, x*x, red4, d);
  float m = mv.x*(1.f/128.f);
  float v = mv.y*(1.f/128.f) - m*m;
  sn[d] = (x - m)*rsqrtf(v + 1e-5f)*g_s[d] + b_s[d];
  __syncthreads();
  float qv = 0.f;
#pragma unroll 4
  for (int e = 0; e < 128; ++e) qv += sn[e]*WqT[e*128 + d];
  qg[row*128 + d] = qv;
  float2 qb = bred128(qv*biasArr[d], 0.f, red4, d);
  if (d == 0) { qkb[row] = qb.x; Ssum[row] = 0.f; }
}

// ---- 6. fused attention iteration: dots+softmax+update-partials ----
// grid: 256 = b(8) x chunk(32 of 128 n). alpha computed inline.
__global__ __launch_bounds__(256) void attn_fused_k(
    const float* __restrict__ KV, const float* __restrict__ qg,
    const float* __restrict__ qkb, const float* __restrict__ varArr,
    const float* __restrict__ denomArr, const float* __restrict__ pm,
    float* __restrict__ Upart, float* __restrict__ Ssum,
    float* __restrict__ outG, int last)
{
  __shared__ float KVs[32*260];
  __shared__ float qs[2048];
  __shared__ float was[16*33];
  __shared__ float qkbs[16];
  int bi = blockIdx.x;
  int b = bi & 7, ch = bi >> 3;
  int t = threadIdx.x;
#pragma unroll
  for (int s = 0; s < 2; ++s)
    ((float4*)qs)[s*256 + t] = ((const float4*)(qg + b*2048))[s*256 + t];
  if (t < 16) qkbs[t] = qkb[b*16 + t];
  int p = t >> 5, nl = t & 31;
  int iu = t >> 4, dg = t & 15;
  int bk = b*8 + p;
  float den = denomArr[bk];
  float acc8[8];
#pragma unroll
  for (int j = 0; j < 8; ++j) acc8[j] = 0.f;
  float sA0 = 0.f, sA1 = 0.f;
  const float* q0 = qs + (p*2)*128;
  const float* q1 = q0 + 128;
  __syncthreads();
  float qb0 = qkbs[p*2], qb1 = qkbs[p*2 + 1];
  for (int sub = 0; sub < 4; ++sub) {
    int n0 = ch*128 + sub*32;
    if (sub) __syncthreads();
    {
      int nn = t >> 3;
      int jj = t & 7;
#pragma unroll
      for (int s = 0; s < 8; ++s) {
        int j4 = jj + s*8;
        *(float4*)&KVs[nn*260 + j4*4] =
          *(const float4*)&KV[((size_t)(b*4096 + n0 + nn))*256 + j4*4];
      }
    }
    __syncthreads();
    float d0 = 0.f, d1 = 0.f;
    const float* kr = KVs + nl*260;
#pragma unroll 8
    for (int j4 = 0; j4 < 32; ++j4) {
      float4 kv = *(const float4*)(kr + j4*4);
      float4 qa = *(const float4*)(q0 + j4*4);
      float4 qb = *(const float4*)(q1 + j4*4);
      d0 += kv.x*qa.x + kv.y*qa.y + kv.z*qa.z + kv.w*qa.w;
      d1 += kv.x*qb.x + kv.y*qb.y + kv.z*qb.z + kv.w*qb.w;
    }
    int n = n0 + nl;
    float pmv = pm[(size_t)bk*4096 + n];
    float c = (den > 1e-6f) ? (pmv/(den + 1e-6f)) : 1.f;
    float vv = varArr[b*4096 + n];
    float al = c*rsqrtf(c*c*vv + 1e-5f);
    float dd0 = SCALE_*(al*d0 + qb0);
    float dd1 = SCALE_*(al*d1 + qb1);
    float mx = fmaxf(dd0, dd1);
    float e0 = expf(dd0 - mx), e1 = expf(dd1 - mx);
    float inv = 1.f/(e0 + e1);
    float o0 = e0*inv + 1e-8f;
    float o1 = e1*inv + 1e-8f;
    sA0 += o0; sA1 += o1;
    was[(p*2)*33 + nl] = o0*al;
    was[(p*2 + 1)*33 + nl] = o1*al;
    if (last) {
      outG[((size_t)(bk*2))*4096 + n] = o0*pmv;
      outG[((size_t)(bk*2 + 1))*4096 + n] = o1*pmv;
    }
    __syncthreads();
    const float* vb = KVs + 128 + dg*8;
    const float* wr = was + iu*33;
#pragma unroll 8
    for (int nn = 0; nn < 32; ++nn) {
      float wv = wr[nn];
      float4 v0 = *(const float4*)(vb + nn*260);
      float4 v1 = *(const float4*)(vb + nn*260 + 4);
      acc8[0] += wv*v0.x; acc8[1] += wv*v0.y; acc8[2] += wv*v0.z; acc8[3] += wv*v0.w;
      acc8[4] += wv*v1.x; acc8[5] += wv*v1.y; acc8[6] += wv*v1.z; acc8[7] += wv*v1.w;
    }
  }
#pragma unroll
  for (int m = 16; m >= 1; m >>= 1) {
    sA0 += __shfl_xor(sA0, m, 32);
    sA1 += __shfl_xor(sA1, m, 32);
  }
  if (nl == 0) {
    atomicAdd(&Ssum[bk*2], sA0);
    atomicAdd(&Ssum[bk*2 + 1], sA1);
  }
  float* up = Upart + ((size_t)(bi*16 + iu))*128 + dg*8;
  *(float4*)up = make_float4(acc8[0], acc8[1], acc8[2], acc8[3]);
  *(float4*)(up + 4) = make_float4(acc8[4], acc8[5], acc8[6], acc8[7]);
}

// ---- 7. GRU + MLP + (LN_s + q for next iter) ----
__global__ __launch_bounds__(128) void gru_mlp_q_k(
    const float* __restrict__ Upart, const float* __restrict__ biasArr,
    const float* __restrict__ WihT, const float* __restrict__ WhhT,
    const float* __restrict__ bih, const float* __restrict__ bhh,
    const float* __restrict__ mlp_g, const float* __restrict__ mlp_b,
    const float* __restrict__ W1T, const float* __restrict__ b1,
    const float* __restrict__ W2T, const float* __restrict__ b2,
    const float* __restrict__ ln_s_g, const float* __restrict__ ln_s_b,
    const float* __restrict__ WqT,
    float* __restrict__ slots, float* __restrict__ qg, float* __restrict__ qkb,
    float* __restrict__ Ssum, float* __restrict__ outObj, int last)
{
  __shared__ float xs[128], hs[128], hn[128], t1s[512];
  __shared__ float red4[4];
  int row = blockIdx.x, d = threadIdx.x;
  float ua = 0.f;
#pragma unroll 4
  for (int ch = 0; ch < 32; ++ch) ua += Upart[(size_t)ch*16384 + row*128 + d];
  float u = ua/Ssum[row] + biasArr[128 + d];
  float h0 = slots[row*128 + d];
  xs[d] = u; hs[d] = h0;
  __syncthreads();
  float gir = bih[d], giz = bih[128 + d], gin = bih[256 + d];
  float ghr = bhh[d], ghz = bhh[128 + d], ghn = bhh[256 + d];
#pragma unroll 2
  for (int e = 0; e < 128; ++e) {
    float x = xs[e], hh = hs[e];
    const float* wi = WihT + e*384 + d;
    const float* wh = WhhT + e*384 + d;
    gir += x*wi[0];  giz += x*wi[128];  gin += x*wi[256];
    ghr += hh*wh[0]; ghz += hh*wh[128]; ghn += hh*wh[256];
  }
  float r = 1.f/(1.f + expf(-(gir + ghr)));
  float z = 1.f/(1.f + expf(-(giz + ghz)));
  float nnv = tanhf(gin + r*ghn);
  float hp = (1.f - z)*nnv + z*h0;
  float2 mv = bred128(hp, hp*hp, red4, d);
  float m = mv.x*(1.f/128.f);
  float v = mv.y*(1.f/128.f) - m*m;
  hn[d] = (hp - m)*rsqrtf(v + 1e-5f)*mlp_g[d] + mlp_b[d];
  __syncthreads();
  float a0 = b1[d], a1 = b1[128 + d], a2 = b1[256 + d], a3 = b1[384 + d];
#pragma unroll 2
  for (int f = 0; f < 128; ++f) {
    float hv = hn[f];
    const float* wr = W1T + f*512 + d;
    a0 += hv*wr[0]; a1 += hv*wr[128]; a2 += hv*wr[256]; a3 += hv*wr[384];
  }
  t1s[d]       = 0.5f*a0*(1.f + erff(a0*0.70710678118654752f));
  t1s[128 + d] = 0.5f*a1*(1.f + erff(a1*0.70710678118654752f));
  t1s[256 + d] = 0.5f*a2*(1.f + erff(a2*0.70710678118654752f));
  t1s[384 + d] = 0.5f*a3*(1.f + erff(a3*0.70710678118654752f));
  __syncthreads();
  float o = b2[d];
#pragma unroll 4
  for (int e = 0; e < 512; ++e) o += t1s[e]*W2T[e*128 + d];
  slots[row*128 + d] = o;
  if (last) { outObj[row*128 + d] = o; return; }
  float2 mv2 = bred128(o, o*o, red4, d);
  float m2 = mv2.x*(1.f/128.f);
  float v2 = mv2.y*(1.f/128.f) - m2*m2;
  float snd = (o - m2)*rsqrtf(v2 + 1e-5f)*ln_s_g[d] + ln_s_b[d];
  __syncthreads();
  xs[d] = snd;
  __syncthreads();
  float qv = 0.f;
#pragma unroll 4
  for (int e = 0; e < 128; ++e) qv += xs[e]*WqT[e*128 + d];
  qg[row*128 + d] = qv;
  float2 qbv = bred128(qv*biasArr[d], 0.f, red4, d);
  if (d == 0) { qkb[row] = qbv.x; Ssum[row] = 0.f; }
}

extern "C" void kernel_launch(void* const* d_in, const int* in_sizes, int n_in,
                              void* d_out, int out_size, void* d_ws, size_t ws_size,
                              hipStream_t stream) {
  const float* tokens = (const float*)d_in[0];
  const float* pslots = (const float*)d_in[1];
  const float* pmasks = (const float*)d_in[2];
  const float* eps    = (const float*)d_in[3];
  const float* ln_in_g= (const float*)d_in[4];
  const float* ln_in_b= (const float*)d_in[5];
  const float* ln_s_g = (const float*)d_in[6];
  const float* ln_s_b = (const float*)d_in[7];
  const float* Wq     = (const float*)d_in[8];
  const float* Wk     = (const float*)d_in[9];
  const float* Wv     = (const float*)d_in[10];
  const float* Wih    = (const float*)d_in[11];
  const float* Whh    = (const float*)d_in[12];
  const float* bih    = (const float*)d_in[13];
  const float* bhh    = (const float*)d_in[14];
  const float* mlp_g  = (const float*)d_in[15];
  const float* mlp_b  = (const float*)d_in[16];
  const float* W1     = (const float*)d_in[17];
  const float* b1     = (const float*)d_in[18];
  const float* W2     = (const float*)d_in[19];
  const float* b2     = (const float*)d_in[20];
  float* ws  = (float*)d_ws;
  float* out = (float*)d_out;
  unsigned short* w2bf = (unsigned short*)(ws + OFF_W2BF);

  prep_w_k<<<256, 64, 0, stream>>>(Wk, Wv, ln_in_g, ln_in_b,
                                   w2bf, ws + OFF_GSUM, ws + OFF_BIAS);
  prep_T_k<<<960, 256, 0, stream>>>(Wq, Wih, Whh, W1, W2,
                                    ws + OFF_WQT, ws + OFF_WIHT, ws + OFF_WHHT,
                                    ws + OFF_W1T, ws + OFF_W2T);
  denom_k<<<64, 256, 0, stream>>>(pmasks, ws + OFF_DENOM);
  gemm_kv_k<<<512, 256, 0, stream>>>(tokens, w2bf, ws + OFF_GSUM,
                                     ws + OFF_KV, ws + OFF_VAR);
  slots_init_q_k<<<128, 128, 0, stream>>>(pslots, eps, ln_s_g, ln_s_b,
                                          ws + OFF_WQT, ws + OFF_BIAS,
                                          ws + OFF_SLOTS, ws + OFF_Q,
                                          ws + OFF_QKB, ws + OFF_SSUM);
  for (int it = 0; it < 3; ++it) {
    int last = (it == 2);
    attn_fused_k<<<256, 256, 0, stream>>>(ws + OFF_KV, ws + OFF_Q, ws + OFF_QKB,
                                          ws + OFF_VAR, ws + OFF_DENOM, pmasks,
                                          ws + OFF_UPART, ws + OFF_SSUM,
                                          out + 16384, last);
    gru_mlp_q_k<<<128, 128, 0, stream>>>(ws + OFF_UPART, ws + OFF_BIAS,
                                         ws + OFF_WIHT, ws + OFF_WHHT, bih, bhh,
                                         mlp_g, mlp_b, ws + OFF_W1T, b1,
                                         ws + OFF_W2T, b2, ln_s_g, ln_s_b,
                                         ws + OFF_WQT,
                                         ws + OFF_SLOTS, ws + OFF_Q, ws + OFF_QKB,
                                         ws + OFF_SSUM, out, last);
  }
}

// Round 3
// 380.904 us; speedup vs baseline: 1.7948x; 1.4216x over previous
//
#include <hip/hip_runtime.h>
#include <math.h>

#define SCALE_ 0.08838834764831843f

typedef __attribute__((ext_vector_type(8))) short bf16x8;
typedef __attribute__((ext_vector_type(4))) float f32x4;

// ---- workspace layout (float offsets) ----
static const size_t OFF_VAR   = 0;        // 32768  var(tokens) per (b,n)
static const size_t OFF_DENOM = 32768;    // 64
static const size_t OFF_GSUM  = 32832;    // 256  sum_k g*W  (K|V)
static const size_t OFF_BIAS  = 33088;    // 256  sum_k b*W  (Kbias|Vbias)
static const size_t OFF_QKB   = 33344;    // 128  q·Kbias per slot row
static const size_t OFF_SSUM  = 33472;    // 128
static const size_t OFF_SLOTS = 33600;    // 16384 [row][128]
static const size_t OFF_Q     = 49984;    // 16384
static const size_t OFF_WQT   = 66368;    // 16384 fp32 WqT (slots_init only)
static const size_t OFF_WQBF  = 82752;    // 8192 slots (16384 bf16) Wq[128][128]
static const size_t OFF_WIHBF = 90944;    // 24576 slots Wih[384][128] bf16
static const size_t OFF_WHHBF = 115520;   // 24576 slots Whh[384][128] bf16
static const size_t OFF_W1BF  = 140096;   // 32768 slots W1[512][128] bf16
static const size_t OFF_WM2BF = 172864;   // 32768 slots W2[128][512] bf16
static const size_t OFF_WKVBF = 205632;   // 98304 slots (196608 bf16) [256][768]
static const size_t OFF_UPART = 303936;   // 524288 [256][16][128]
static const size_t OFF_KV    = 828224;   // 8388608 [b][n][256] (K|V)

__device__ __forceinline__ float wred64(float v) {
#pragma unroll
  for (int off = 32; off > 0; off >>= 1) v += __shfl_xor(v, off, 64);
  return v;
}

__device__ __forceinline__ float2 bred128(float a, float b, float* red4, int t) {
  float ra = wred64(a), rb = wred64(b);
  int wid = t >> 6;
  if ((t & 63) == 0) { red4[wid] = ra; red4[2 + wid] = rb; }
  __syncthreads();
  float2 o; o.x = red4[0] + red4[1]; o.y = red4[2] + red4[3];
  __syncthreads();
  return o;
}

__device__ __forceinline__ unsigned short f2bf(float f) {
  unsigned u = __float_as_uint(f);
  unsigned r = (u + 0x7fffu + ((u >> 16) & 1u)) >> 16;
  return (unsigned short)r;
}

__device__ __forceinline__ unsigned pack2(float a, float b) {
  return (unsigned)f2bf(a) | ((unsigned)f2bf(b) << 16);
}

// ---- 1. fold ln gain into W (bf16) + gsum/bias sums ----
__global__ __launch_bounds__(64) void prep_w_k(
    const float* __restrict__ Wk, const float* __restrict__ Wv,
    const float* __restrict__ g, const float* __restrict__ bb,
    unsigned short* __restrict__ wkv, float* __restrict__ gsum,
    float* __restrict__ biasArr)
{
  int j = blockIdx.x, lane = threadIdx.x;
  const float* w = (j < 128) ? (Wk + (size_t)j*768) : (Wv + (size_t)(j-128)*768);
  float gs = 0.f, bs = 0.f;
#pragma unroll
  for (int s = 0; s < 12; ++s) {
    int dd = lane + s*64;
    float wv = w[dd], gv = g[dd];
    gs += gv*wv; bs += bb[dd]*wv;
    wkv[(size_t)j*768 + dd] = f2bf(wv*gv);
  }
  gs = wred64(gs); bs = wred64(bs);
  if (lane == 0) { gsum[j] = gs; biasArr[j] = bs; }
}

// ---- 2. WqT fp32 (for slots_init) + bf16 copies of slot-path weights ----
__global__ __launch_bounds__(256) void prep_bf_k(
    const float* __restrict__ Wq, const float* __restrict__ Wih,
    const float* __restrict__ Whh, const float* __restrict__ W1,
    const float* __restrict__ W2,
    float* __restrict__ WqT, unsigned short* __restrict__ Wqbf,
    unsigned short* __restrict__ Wihbf, unsigned short* __restrict__ Whhbf,
    unsigned short* __restrict__ W1bf, unsigned short* __restrict__ Wm2bf)
{
  int bi = blockIdx.x, t = threadIdx.x;
  if (bi < 64) {
    int idx = bi*256 + t;
    int r = idx >> 7, c = idx & 127;
    WqT[(size_t)c*128 + r] = Wq[idx];
    Wqbf[idx] = f2bf(Wq[idx]);
    return;
  }
  const float* src; unsigned short* dst; int idx;
  if (bi < 256)      { src = Wih; dst = Wihbf; idx = (bi-64)*256 + t; }
  else if (bi < 448) { src = Whh; dst = Whhbf; idx = (bi-256)*256 + t; }
  else if (bi < 704) { src = W1;  dst = W1bf;  idx = (bi-448)*256 + t; }
  else               { src = W2;  dst = Wm2bf; idx = (bi-704)*256 + t; }
  dst[idx] = f2bf(src[idx]);
}

// ---- 3. denom[bk] = mean(parent_masks over N) ----
__global__ __launch_bounds__(256) void denom_k(
    const float* __restrict__ pm, float* __restrict__ denomArr)
{
  __shared__ float red4[4];
  int bk = blockIdx.x, t = threadIdx.x;
  float s = 0.f;
#pragma unroll
  for (int k = 0; k < 16; ++k) s += pm[bk*4096 + t + k*256];
  s = wred64(s);
  if ((t & 63) == 0) red4[t >> 6] = s;
  __syncthreads();
  if (t == 0) denomArr[bk] = (red4[0]+red4[1]+red4[2]+red4[3])*(1.f/4096.f);
}

// ---- 4. MFMA GEMM: tokens -> KV [b][n][256] (+ var) ----
__global__ __launch_bounds__(256) void gemm_kv_k(
    const float* __restrict__ tokens, const unsigned short* __restrict__ wkv,
    const float* __restrict__ gsum, float* __restrict__ KV,
    float* __restrict__ varArr)
{
  __shared__ unsigned short As[128*64];
  __shared__ unsigned short Bs[128*64];
  int bi = blockIdx.x;
  int jb = bi & 1, rb = bi >> 1;
  int r0 = rb*128, j0 = jb*128;
  int t = threadIdx.x;
  int w = t >> 6, lane = t & 63;
  int j4 = t & 15, rowb = t >> 4;
  int m0w = (w >> 1)*64, n0w = (w & 1)*64;
  int lm = lane & 15, lq = lane >> 4;

  f32x4 acc[4][4];
#pragma unroll
  for (int a = 0; a < 4; ++a)
#pragma unroll
    for (int c = 0; c < 4; ++c) acc[a][c] = f32x4{0.f, 0.f, 0.f, 0.f};

  float s1[8], s2[8];
#pragma unroll
  for (int s = 0; s < 8; ++s) { s1[s] = 0.f; s2[s] = 0.f; }

  for (int k0 = 0; k0 < 768; k0 += 64) {
    __syncthreads();
#pragma unroll
    for (int s = 0; s < 4; ++s) {
      int row = w*32 + s*8;
      __builtin_amdgcn_global_load_lds(
        (const __attribute__((address_space(1))) void*)
          (wkv + (size_t)(j0 + row + (lane >> 3))*768 + k0 + (lane & 7)*8),
        (__attribute__((address_space(3))) void*)(&Bs[row*64]), 16, 0, 0);
    }
#pragma unroll
    for (int s = 0; s < 8; ++s) {
      int row = rowb + s*16;
      float4 x = *(const float4*)(tokens + (size_t)(r0 + row)*768 + k0 + j4*4);
      s1[s] += x.x + x.y + x.z + x.w;
      s2[s] += x.x*x.x + x.y*x.y + x.z*x.z + x.w*x.w;
      *(uint2*)(&As[row*64 + j4*4]) = make_uint2(pack2(x.x, x.y), pack2(x.z, x.w));
    }
    __syncthreads();
#pragma unroll
    for (int kk = 0; kk < 64; kk += 32) {
      bf16x8 af[4], bfr[4];
#pragma unroll
      for (int mt = 0; mt < 4; ++mt)
        af[mt] = *(const bf16x8*)(&As[(m0w + mt*16 + lm)*64 + kk + lq*8]);
#pragma unroll
      for (int nt = 0; nt < 4; ++nt)
        bfr[nt] = *(const bf16x8*)(&Bs[(n0w + nt*16 + lm)*64 + kk + lq*8]);
#pragma unroll
      for (int mt = 0; mt < 4; ++mt)
#pragma unroll
        for (int nt = 0; nt < 4; ++nt)
          acc[mt][nt] = __builtin_amdgcn_mfma_f32_16x16x32_bf16(
              af[mt], bfr[nt], acc[mt][nt], 0, 0, 0);
    }
  }
  __syncthreads();
  float* meanS = (float*)As;
#pragma unroll
  for (int s = 0; s < 8; ++s) {
#pragma unroll
    for (int m = 8; m >= 1; m >>= 1) {
      s1[s] += __shfl_xor(s1[s], m, 16);
      s2[s] += __shfl_xor(s2[s], m, 16);
    }
  }
  if (j4 == 0) {
#pragma unroll
    for (int s = 0; s < 8; ++s) {
      int row = rowb + s*16;
      float m = s1[s]*(1.f/768.f);
      meanS[row] = m;
      if (jb == 0) varArr[r0 + row] = s2[s]*(1.f/768.f) - m*m;
    }
  }
  __syncthreads();
#pragma unroll
  for (int nt = 0; nt < 4; ++nt) {
    int jg = j0 + n0w + nt*16 + lm;
    float gs = gsum[jg];
#pragma unroll
    for (int mt = 0; mt < 4; ++mt) {
#pragma unroll
      for (int reg = 0; reg < 4; ++reg) {
        int rl = m0w + mt*16 + lq*4 + reg;
        KV[(size_t)(r0 + rl)*256 + jg] = acc[mt][nt][reg] - meanS[rl]*gs;
      }
    }
  }
}

// ---- 5. slots init + LN + q (iter 0) ----
__global__ __launch_bounds__(128) void slots_init_q_k(
    const float* __restrict__ ps, const float* __restrict__ eps,
    const float* __restrict__ g_s, const float* __restrict__ b_s,
    const float* __restrict__ WqT, const float* __restrict__ biasArr,
    float* __restrict__ slots, float* __restrict__ qg, float* __restrict__ qkb,
    float* __restrict__ Ssum)
{
  __shared__ float sn[128];
  __shared__ float red4[4];
  int row = blockIdx.x, d = threadIdx.x, bk = row >> 1;
  float x = ps[bk*128 + d] + 0.01f*eps[row*128 + d];
  slots[row*128 + d] = x;
  float2 mv = bred128(x, x*x, red4, d);
  float m = mv.x*(1.f/128.f);
  float v = mv.y*(1.f/128.f) - m*m;
  sn[d] = (x - m)*rsqrtf(v + 1e-5f)*g_s[d] + b_s[d];
  __syncthreads();
  float qv = 0.f;
#pragma unroll 4
  for (int e = 0; e < 128; ++e) qv += sn[e]*WqT[e*128 + d];
  qg[row*128 + d] = qv;
  float2 qb = bred128(qv*biasArr[d], 0.f, red4, d);
  if (d == 0) { qkb[row] = qb.x; Ssum[row] = 0.f; }
}

// ---- 6. fused attention iteration ----
__global__ __launch_bounds__(256) void attn_fused_k(
    const float* __restrict__ KV, const float* __restrict__ qg,
    const float* __restrict__ qkb, const float* __restrict__ varArr,
    const float* __restrict__ denomArr, const float* __restrict__ pm,
    float* __restrict__ Upart, float* __restrict__ Ssum,
    float* __restrict__ outG, int last)
{
  __shared__ float KVs[32*260];
  __shared__ float qs[2048];
  __shared__ float was[16*33];
  __shared__ float qkbs[16];
  int bi = blockIdx.x;
  int b = bi & 7, ch = bi >> 3;
  int t = threadIdx.x;
#pragma unroll
  for (int s = 0; s < 2; ++s)
    ((float4*)qs)[s*256 + t] = ((const float4*)(qg + b*2048))[s*256 + t];
  if (t < 16) qkbs[t] = qkb[b*16 + t];
  int p = t >> 5, nl = t & 31;
  int iu = t >> 4, dg = t & 15;
  int bk = b*8 + p;
  float den = denomArr[bk];
  float acc8[8];
#pragma unroll
  for (int j = 0; j < 8; ++j) acc8[j] = 0.f;
  float sA0 = 0.f, sA1 = 0.f;
  const float* q0 = qs + (p*2)*128;
  const float* q1 = q0 + 128;
  __syncthreads();
  float qb0 = qkbs[p*2], qb1 = qkbs[p*2 + 1];
  for (int sub = 0; sub < 4; ++sub) {
    int n0 = ch*128 + sub*32;
    if (sub) __syncthreads();
    {
      int nn = t >> 3;
      int jj = t & 7;
#pragma unroll
      for (int s = 0; s < 8; ++s) {
        int j4 = jj + s*8;
        *(float4*)&KVs[nn*260 + j4*4] =
          *(const float4*)&KV[((size_t)(b*4096 + n0 + nn))*256 + j4*4];
      }
    }
    __syncthreads();
    float d0 = 0.f, d1 = 0.f;
    const float* kr = KVs + nl*260;
#pragma unroll 8
    for (int j4 = 0; j4 < 32; ++j4) {
      float4 kv = *(const float4*)(kr + j4*4);
      float4 qa = *(const float4*)(q0 + j4*4);
      float4 qb = *(const float4*)(q1 + j4*4);
      d0 += kv.x*qa.x + kv.y*qa.y + kv.z*qa.z + kv.w*qa.w;
      d1 += kv.x*qb.x + kv.y*qb.y + kv.z*qb.z + kv.w*qb.w;
    }
    int n = n0 + nl;
    float pmv = pm[(size_t)bk*4096 + n];
    float c = (den > 1e-6f) ? (pmv/(den + 1e-6f)) : 1.f;
    float vv = varArr[b*4096 + n];
    float al = c*rsqrtf(c*c*vv + 1e-5f);
    float dd0 = SCALE_*(al*d0 + qb0);
    float dd1 = SCALE_*(al*d1 + qb1);
    float mx = fmaxf(dd0, dd1);
    float e0 = expf(dd0 - mx), e1 = expf(dd1 - mx);
    float inv = 1.f/(e0 + e1);
    float o0 = e0*inv + 1e-8f;
    float o1 = e1*inv + 1e-8f;
    sA0 += o0; sA1 += o1;
    was[(p*2)*33 + nl] = o0*al;
    was[(p*2 + 1)*33 + nl] = o1*al;
    if (last) {
      outG[((size_t)(bk*2))*4096 + n] = o0*pmv;
      outG[((size_t)(bk*2 + 1))*4096 + n] = o1*pmv;
    }
    __syncthreads();
    const float* vb = KVs + 128 + dg*8;
    const float* wr = was + iu*33;
#pragma unroll 8
    for (int nn = 0; nn < 32; ++nn) {
      float wv = wr[nn];
      float4 v0 = *(const float4*)(vb + nn*260);
      float4 v1 = *(const float4*)(vb + nn*260 + 4);
      acc8[0] += wv*v0.x; acc8[1] += wv*v0.y; acc8[2] += wv*v0.z; acc8[3] += wv*v0.w;
      acc8[4] += wv*v1.x; acc8[5] += wv*v1.y; acc8[6] += wv*v1.z; acc8[7] += wv*v1.w;
    }
  }
#pragma unroll
  for (int m = 16; m >= 1; m >>= 1) {
    sA0 += __shfl_xor(sA0, m, 32);
    sA1 += __shfl_xor(sA1, m, 32);
  }
  if (nl == 0) {
    atomicAdd(&Ssum[bk*2], sA0);
    atomicAdd(&Ssum[bk*2 + 1], sA1);
  }
  float* up = Upart + ((size_t)(bi*16 + iu))*128 + dg*8;
  *(float4*)up = make_float4(acc8[0], acc8[1], acc8[2], acc8[3]);
  *(float4*)(up + 4) = make_float4(acc8[4], acc8[5], acc8[6], acc8[7]);
}

// ---- 7. GRU + MLP + next-iter q : MFMA version ----
// 8 blocks x 256 threads (4 waves); block handles 16 slot rows (batch b=blk).
// Weights bf16 in ORIGINAL [out][in] layout -> B-frag = contiguous 16B load.
// Activations staged in LDS pre-arranged in A-fragment order:
// frag element (m,k): kc=k>>5, lane=((k>>3)&3)*16+m, j=k&7.
__global__ __launch_bounds__(256, 1) void gru_mlp_q_k(
    const float* __restrict__ Upart, const float* __restrict__ Ssum,
    const float* __restrict__ biasArr,
    const unsigned short* __restrict__ Wihbf, const unsigned short* __restrict__ Whhbf,
    const float* __restrict__ bih, const float* __restrict__ bhh,
    const float* __restrict__ mlp_g, const float* __restrict__ mlp_b,
    const unsigned short* __restrict__ W1bf, const float* __restrict__ b1,
    const unsigned short* __restrict__ Wm2bf, const float* __restrict__ b2,
    const float* __restrict__ ln_s_g, const float* __restrict__ ln_s_b,
    const unsigned short* __restrict__ Wqbf,
    float* __restrict__ slots, float* __restrict__ qg, float* __restrict__ qkb,
    float* __restrict__ SsumW, float* __restrict__ outObj, int last)
{
  __shared__ unsigned short FXx[2048], FXh[2048], Fhn[2048], Fsn[2048];
  __shared__ unsigned short Ft1[8192];
  __shared__ float G_rz[16*256];
  __shared__ float G_in[16*128];
  __shared__ float G_hn[16*128];
  __shared__ float hs_[16*128];
  __shared__ float os_[16*128];
  __shared__ float qkbL[16];

  int blk = blockIdx.x;          // = batch b
  int R0 = blk*16;
  int t = threadIdx.x;
  int w = t >> 6, ln = t & 63;
  int lm = ln & 15, lq = ln >> 4;

  // ---- phase A: u = sum(Upart)/S + biasV ; h = slots ; build frags ----
  {
    int r = t >> 4, dseg = t & 15, ds8 = dseg*8;
    int R = R0 + r;
    float ua[8];
#pragma unroll
    for (int j = 0; j < 8; ++j) ua[j] = 0.f;
    const float* up = Upart + (size_t)R*128 + ds8;
#pragma unroll 4
    for (int ch = 0; ch < 32; ++ch) {
      float4 u0 = *(const float4*)(up + (size_t)ch*16384);
      float4 u1 = *(const float4*)(up + (size_t)ch*16384 + 4);
      ua[0]+=u0.x; ua[1]+=u0.y; ua[2]+=u0.z; ua[3]+=u0.w;
      ua[4]+=u1.x; ua[5]+=u1.y; ua[6]+=u1.z; ua[7]+=u1.w;
    }
    float Sv = 1.f/Ssum[R];
    float4 bv0 = *(const float4*)(biasArr + 128 + ds8);
    float4 bv1 = *(const float4*)(biasArr + 132 + ds8);
    float xv[8];
    xv[0]=ua[0]*Sv+bv0.x; xv[1]=ua[1]*Sv+bv0.y; xv[2]=ua[2]*Sv+bv0.z; xv[3]=ua[3]*Sv+bv0.w;
    xv[4]=ua[4]*Sv+bv1.x; xv[5]=ua[5]*Sv+bv1.y; xv[6]=ua[6]*Sv+bv1.z; xv[7]=ua[7]*Sv+bv1.w;
    float4 h0 = *(const float4*)(slots + (size_t)R*128 + ds8);
    float4 h1 = *(const float4*)(slots + (size_t)R*128 + ds8 + 4);
    *(float4*)(hs_ + r*128 + ds8) = h0;
    *(float4*)(hs_ + r*128 + ds8 + 4) = h1;
    int fa = ((dseg >> 2)*64 + (dseg & 3)*16 + r)*8;
    *(uint4*)&FXx[fa] = make_uint4(pack2(xv[0],xv[1]), pack2(xv[2],xv[3]),
                                   pack2(xv[4],xv[5]), pack2(xv[6],xv[7]));
    *(uint4*)&FXh[fa] = make_uint4(pack2(h0.x,h0.y), pack2(h0.z,h0.w),
                                   pack2(h1.x,h1.y), pack2(h1.z,h1.w));
    if (t < 16) qkbL[t] = 0.f;
  }
  __syncthreads();

  // ---- phase B: GRU gemms ----
  {
    bf16x8 ax[4], ah[4];
#pragma unroll
    for (int kc = 0; kc < 4; ++kc) {
      ax[kc] = *(const bf16x8*)(&FXx[(kc*64 + ln)*8]);
      ah[kc] = *(const bf16x8*)(&FXh[(kc*64 + ln)*8]);
    }
    if (w < 2) {
      // rz combined: tiles n0 = (w*8+i)*16, both ih and hh into one acc
#pragma unroll
      for (int i = 0; i < 8; ++i) {
        int n0 = (w*8 + i)*16;
        f32x4 acc = f32x4{0.f,0.f,0.f,0.f};
#pragma unroll
        for (int kc = 0; kc < 4; ++kc) {
          bf16x8 bi_ = *(const bf16x8*)(&Wihbf[(size_t)(n0+lm)*128 + kc*32 + lq*8]);
          acc = __builtin_amdgcn_mfma_f32_16x16x32_bf16(ax[kc], bi_, acc, 0,0,0);
        }
#pragma unroll
        for (int kc = 0; kc < 4; ++kc) {
          bf16x8 bh_ = *(const bf16x8*)(&Whhbf[(size_t)(n0+lm)*128 + kc*32 + lq*8]);
          acc = __builtin_amdgcn_mfma_f32_16x16x32_bf16(ah[kc], bh_, acc, 0,0,0);
        }
#pragma unroll
        for (int reg = 0; reg < 4; ++reg)
          G_rz[(lq*4+reg)*256 + n0 + lm] = acc[reg];
      }
    } else if (w == 2) {
      // in gate: x @ Wih rows 256..383
#pragma unroll
      for (int i = 0; i < 8; ++i) {
        int n0 = 256 + i*16;
        f32x4 acc = f32x4{0.f,0.f,0.f,0.f};
#pragma unroll
        for (int kc = 0; kc < 4; ++kc) {
          bf16x8 bi_ = *(const bf16x8*)(&Wihbf[(size_t)(n0+lm)*128 + kc*32 + lq*8]);
          acc = __builtin_amdgcn_mfma_f32_16x16x32_bf16(ax[kc], bi_, acc, 0,0,0);
        }
#pragma unroll
        for (int reg = 0; reg < 4; ++reg)
          G_in[(lq*4+reg)*128 + i*16 + lm] = acc[reg];
      }
    } else {
      // hn gate: h @ Whh rows 256..383
#pragma unroll
      for (int i = 0; i < 8; ++i) {
        int n0 = 256 + i*16;
        f32x4 acc = f32x4{0.f,0.f,0.f,0.f};
#pragma unroll
        for (int kc = 0; kc < 4; ++kc) {
          bf16x8 bh_ = *(const bf16x8*)(&Whhbf[(size_t)(n0+lm)*128 + kc*32 + lq*8]);
          acc = __builtin_amdgcn_mfma_f32_16x16x32_bf16(ah[kc], bh_, acc, 0,0,0);
        }
#pragma unroll
        for (int reg = 0; reg < 4; ++reg)
          G_hn[(lq*4+reg)*128 + i*16 + lm] = acc[reg];
      }
    }
  }
  __syncthreads();

  // ---- phase C: elementwise GRU + LN -> Fhn frags ----
  {
    int r = t >> 4, dseg = t & 15, ds8 = dseg*8;
    float hp[8];
    float s1 = 0.f, s2 = 0.f;
#pragma unroll
    for (int j = 0; j < 8; ++j) {
      int d = ds8 + j;
      float rg = G_rz[r*256 + d] + bih[d] + bhh[d];
      float zg = G_rz[r*256 + 128 + d] + bih[128+d] + bhh[128+d];
      float ing = G_in[r*128 + d] + bih[256+d];
      float hng = G_hn[r*128 + d] + bhh[256+d];
      float rv = 1.f/(1.f + expf(-rg));
      float zv = 1.f/(1.f + expf(-zg));
      float nv = tanhf(ing + rv*hng);
      float h0 = hs_[r*128 + d];
      float h = (1.f - zv)*nv + zv*h0;
      hp[j] = h;
      s1 += h; s2 += h*h;
    }
#pragma unroll
    for (int m = 8; m >= 1; m >>= 1) {
      s1 += __shfl_xor(s1, m, 16);
      s2 += __shfl_xor(s2, m, 16);
    }
    float mean = s1*(1.f/128.f);
    float var = s2*(1.f/128.f) - mean*mean;
    float rstd = rsqrtf(var + 1e-5f);
    float hv[8];
#pragma unroll
    for (int j = 0; j < 8; ++j) {
      int d = ds8 + j;
      hv[j] = (hp[j] - mean)*rstd*mlp_g[d] + mlp_b[d];
    }
    int fa = ((dseg >> 2)*64 + (dseg & 3)*16 + r)*8;
    *(uint4*)&Fhn[fa] = make_uint4(pack2(hv[0],hv[1]), pack2(hv[2],hv[3]),
                                   pack2(hv[4],hv[5]), pack2(hv[6],hv[7]));
  }
  __syncthreads();

  // ---- phase D: MLP1 + gelu -> Ft1 frags ----
  {
    bf16x8 af[4];
#pragma unroll
    for (int kc = 0; kc < 4; ++kc)
      af[kc] = *(const bf16x8*)(&Fhn[(kc*64 + ln)*8]);
#pragma unroll
    for (int i = 0; i < 8; ++i) {
      int n0 = (w*8 + i)*16;
      f32x4 acc = f32x4{0.f,0.f,0.f,0.f};
#pragma unroll
      for (int kc = 0; kc < 4; ++kc) {
        bf16x8 bw = *(const bf16x8*)(&W1bf[(size_t)(n0+lm)*128 + kc*32 + lq*8]);
        acc = __builtin_amdgcn_mfma_f32_16x16x32_bf16(af[kc], bw, acc, 0,0,0);
      }
      int kdim = n0 + lm;
      float bb = b1[kdim];
      int kc2 = kdim >> 5;
      int sub = (kdim >> 3) & 3;
      int jj = kdim & 7;
#pragma unroll
      for (int reg = 0; reg < 4; ++reg) {
        float v = acc[reg] + bb;
        float gel = 0.5f*v*(1.f + erff(v*0.70710678118654752f));
        Ft1[(kc2*64 + sub*16 + lq*4 + reg)*8 + jj] = f2bf(gel);
      }
    }
  }
  __syncthreads();

  // ---- phase E: MLP2 -> slots (+out), os_ ----
  {
#pragma unroll
    for (int i = 0; i < 2; ++i) {
      int n0 = w*32 + i*16;
      f32x4 acc = f32x4{0.f,0.f,0.f,0.f};
#pragma unroll
      for (int kc = 0; kc < 16; ++kc) {
        bf16x8 af = *(const bf16x8*)(&Ft1[(kc*64 + ln)*8]);
        bf16x8 bw = *(const bf16x8*)(&Wm2bf[(size_t)(n0+lm)*512 + kc*32 + lq*8]);
        acc = __builtin_amdgcn_mfma_f32_16x16x32_bf16(af, bw, acc, 0,0,0);
      }
      int n = n0 + lm;
      float bb = b2[n];
#pragma unroll
      for (int reg = 0; reg < 4; ++reg) {
        int row = lq*4 + reg;
        float o = acc[reg] + bb;
        slots[(size_t)(R0 + row)*128 + n] = o;
        os_[row*128 + n] = o;
        if (last) outObj[(size_t)(R0 + row)*128 + n] = o;
      }
    }
  }

  if (last) return;

  __syncthreads();
  // ---- phase F1: LN(slots) -> Fsn frags ----
  {
    int r = t >> 4, dseg = t & 15, ds8 = dseg*8;
    float ov[8];
    float s1 = 0.f, s2 = 0.f;
#pragma unroll
    for (int j = 0; j < 8; ++j) {
      float o = os_[r*128 + ds8 + j];
      ov[j] = o; s1 += o; s2 += o*o;
    }
#pragma unroll
    for (int m = 8; m >= 1; m >>= 1) {
      s1 += __shfl_xor(s1, m, 16);
      s2 += __shfl_xor(s2, m, 16);
    }
    float mean = s1*(1.f/128.f);
    float var = s2*(1.f/128.f) - mean*mean;
    float rstd = rsqrtf(var + 1e-5f);
    float sv[8];
#pragma unroll
    for (int j = 0; j < 8; ++j) {
      int d = ds8 + j;
      sv[j] = (ov[j] - mean)*rstd*ln_s_g[d] + ln_s_b[d];
    }
    int fa = ((dseg >> 2)*64 + (dseg & 3)*16 + r)*8;
    *(uint4*)&Fsn[fa] = make_uint4(pack2(sv[0],sv[1]), pack2(sv[2],sv[3]),
                                   pack2(sv[4],sv[5]), pack2(sv[6],sv[7]));
  }
  __syncthreads();

  // ---- phase F2: q = sn @ Wq^T ; qkb = q . biasK ----
  {
    bf16x8 af[4];
#pragma unroll
    for (int kc = 0; kc < 4; ++kc)
      af[kc] = *(const bf16x8*)(&Fsn[(kc*64 + ln)*8]);
    float pr[4] = {0.f, 0.f, 0.f, 0.f};
#pragma unroll
    for (int i = 0; i < 2; ++i) {
      int n0 = w*32 + i*16;
      f32x4 acc = f32x4{0.f,0.f,0.f,0.f};
#pragma unroll
      for (int kc = 0; kc < 4; ++kc) {
        bf16x8 bw = *(const bf16x8*)(&Wqbf[(size_t)(n0+lm)*128 + kc*32 + lq*8]);
        acc = __builtin_amdgcn_mfma_f32_16x16x32_bf16(af[kc], bw, acc, 0,0,0);
      }
      int n = n0 + lm;
      float bk_ = biasArr[n];
#pragma unroll
      for (int reg = 0; reg < 4; ++reg) {
        int row = lq*4 + reg;
        qg[(size_t)(R0 + row)*128 + n] = acc[reg];
        pr[reg] += acc[reg]*bk_;
      }
    }
#pragma unroll
    for (int reg = 0; reg < 4; ++reg) {
#pragma unroll
      for (int m = 8; m >= 1; m >>= 1) pr[reg] += __shfl_xor(pr[reg], m, 16);
    }
    if (lm == 0) {
#pragma unroll
      for (int reg = 0; reg < 4; ++reg)
        atomicAdd(&qkbL[lq*4 + reg], pr[reg]);
    }
  }
  __syncthreads();
  if (t < 16) {
    qkb[R0 + t] = qkbL[t];
    SsumW[R0 + t] = 0.f;
  }
}

extern "C" void kernel_launch(void* const* d_in, const int* in_sizes, int n_in,
                              void* d_out, int out_size, void* d_ws, size_t ws_size,
                              hipStream_t stream) {
  const float* tokens = (const float*)d_in[0];
  const float* pslots = (const float*)d_in[1];
  const float* pmasks = (const float*)d_in[2];
  const float* eps    = (const float*)d_in[3];
  const float* ln_in_g= (const float*)d_in[4];
  const float* ln_in_b= (const float*)d_in[5];
  const float* ln_s_g = (const float*)d_in[6];
  const float* ln_s_b = (const float*)d_in[7];
  const float* Wq     = (const float*)d_in[8];
  const float* Wk     = (const float*)d_in[9];
  const float* Wv     = (const float*)d_in[10];
  const float* Wih    = (const float*)d_in[11];
  const float* Whh    = (const float*)d_in[12];
  const float* bih    = (const float*)d_in[13];
  const float* bhh    = (const float*)d_in[14];
  const float* mlp_g  = (const float*)d_in[15];
  const float* mlp_b  = (const float*)d_in[16];
  const float* W1     = (const float*)d_in[17];
  const float* b1     = (const float*)d_in[18];
  const float* W2     = (const float*)d_in[19];
  const float* b2     = (const float*)d_in[20];
  float* ws  = (float*)d_ws;
  float* out = (float*)d_out;
  unsigned short* wkvbf = (unsigned short*)(ws + OFF_WKVBF);
  unsigned short* wqbf  = (unsigned short*)(ws + OFF_WQBF);
  unsigned short* wihbf = (unsigned short*)(ws + OFF_WIHBF);
  unsigned short* whhbf = (unsigned short*)(ws + OFF_WHHBF);
  unsigned short* w1bf  = (unsigned short*)(ws + OFF_W1BF);
  unsigned short* wm2bf = (unsigned short*)(ws + OFF_WM2BF);

  prep_w_k<<<256, 64, 0, stream>>>(Wk, Wv, ln_in_g, ln_in_b,
                                   wkvbf, ws + OFF_GSUM, ws + OFF_BIAS);
  prep_bf_k<<<960, 256, 0, stream>>>(Wq, Wih, Whh, W1, W2,
                                     ws + OFF_WQT, wqbf, wihbf, whhbf,
                                     w1bf, wm2bf);
  denom_k<<<64, 256, 0, stream>>>(pmasks, ws + OFF_DENOM);
  gemm_kv_k<<<512, 256, 0, stream>>>(tokens, wkvbf, ws + OFF_GSUM,
                                     ws + OFF_KV, ws + OFF_VAR);
  slots_init_q_k<<<128, 128, 0, stream>>>(pslots, eps, ln_s_g, ln_s_b,
                                          ws + OFF_WQT, ws + OFF_BIAS,
                                          ws + OFF_SLOTS, ws + OFF_Q,
                                          ws + OFF_QKB, ws + OFF_SSUM);
  for (int it = 0; it < 3; ++it) {
    int last = (it == 2);
    attn_fused_k<<<256, 256, 0, stream>>>(ws + OFF_KV, ws + OFF_Q, ws + OFF_QKB,
                                          ws + OFF_VAR, ws + OFF_DENOM, pmasks,
                                          ws + OFF_UPART, ws + OFF_SSUM,
                                          out + 16384, last);
    gru_mlp_q_k<<<8, 256, 0, stream>>>(ws + OFF_UPART, ws + OFF_SSUM,
                                       ws + OFF_BIAS, wihbf, whhbf, bih, bhh,
                                       mlp_g, mlp_b, w1bf, b1, wm2bf, b2,
                                       ln_s_g, ln_s_b, wqbf,
                                       ws + OFF_SLOTS, ws + OFF_Q, ws + OFF_QKB,
                                       ws + OFF_SSUM, out, last);
  }
}